// Round 5
// baseline (402.021 us; speedup 1.0000x reference)
//
#include <hip/hip_runtime.h>
#include <hip/hip_fp16.h>
#include <type_traits>
#include <utility>

#define HH 512
#define WW 512
#define NCH 3
#define NBATCH 16
#define NIMG (NBATCH*NCH)     // 48
#define CHUNK 32              // output rows per wave
#define NCHUNK (HH/CHUNK)     // 16
#define NSTRIP 4              // 128-col strips
#define SW 128
#define SLOTS 140             // cols c0-5 .. c0+132 at slot = col-c0+5
#define NT 64                 // one wave per block -> no barriers anywhere
#define NROWS (CHUNK+10)      // 42 input rows per wave
#define BLKS_PER_B (NCH*NCHUNK*NSTRIP)   // 192 partial slots per batch elem

struct RowData { float4 m; float2 h; };
struct RingR { __half2 a, b, c, d; };    // struct of scalars: SROA-trivial

template<int I, int N, typename F>
__device__ __forceinline__ void sfor(F&& f) {
  if constexpr (I < N) {
    f(std::integral_constant<int, I>{});
    sfor<I + 1, N>(std::forward<F>(f));
  }
}

// R12: register ring, third attempt — both prior failure modes fixed.
//  R9 (scratch): union array defeated SROA -> 11 NAMED structs, if constexpr.
//  R11 (256 VGPR + 300MB spill): full macro expansion removed every loop
//  back-edge -> scheduler hoisted ~42 bodies' loads into giant live ranges.
//  Fix: steady state is a REAL 2-iter loop with unroll(disable); only the
//  inner 11 bodies (compile-time slots) unroll — R10's proven structure.
//  __launch_bounds__(64,3) caps VGPR at 170 (512/SIMD / 3 waves) preserving
//  the 12-waves/CU grid cap. LDS = row dbuf only (2240B): LDS-cap 5 -> 28
//  blocks/CU, grid-cap 12. Arithmetic bit-identical R7/R10 (absmax 0.0).
__global__ __launch_bounds__(NT, 3) void ssim_main(
    const float* __restrict__ pred, const float* __restrict__ targ,
    float* __restrict__ ws)
{
  // row staging, 2 buffers: slot s holds (x,y) of col c0+s-5 (same-wave LDS
  // is in-order; no barriers needed — validated R2-R11, absmax 0.0)
  __shared__ __align__(16) float2 rowb[2][SLOTS];

  const int l = threadIdx.x;
  const int blk = blockIdx.x;
  const int img = blk >> 6;              // / (NCHUNK*NSTRIP)
  const int rem = blk & 63;
  const int chunk = rem >> 2;
  const int strip = rem & 3;

  const int r0 = chunk*CHUNK - 5;        // first input row
  const int c0 = strip*SW;

  // zero the pad slots once in BOTH buffers (image-edge strips keep them zero)
  if (l < 10) {
    const int s = (l < 5) ? l : (128 + l);
    rowb[0][s] = make_float2(0.f, 0.f);
    rowb[1][s] = make_float2(0.f, 0.f);
  }

  const size_t ib = (size_t)img * (size_t)(HH*WW);
  const float* pp = pred + ib;
  const float* tp = targ + ib;

  const int cm = c0 + 2*l;               // this lane's 2 main cols
  const int h  = l - 54;                 // halo id 0..9 on lanes 54..63
  const int ch = (h < 5) ? (c0 - 5 + h) : (c0 + 123 + h);   // halo col
  const bool hval = (l >= 54) && ((unsigned)ch < (unsigned)WW);
  const int hs = (h < 5) ? h : (128 + h);                    // halo slot

  auto loadrow = [&](int it) -> RowData {
    RowData d;
    const int r = r0 + it;
    if ((unsigned)r < (unsigned)HH) {    // wave-uniform branch
      const size_t ro = (size_t)r * WW;
      const float2 x = *(const float2*)(pp + ro + cm);
      const float2 y = *(const float2*)(tp + ro + cm);
      d.m = make_float4(x.x, x.y, y.x, y.y);
      if (hval) d.h = make_float2(pp[ro + ch], tp[ro + ch]);
      else      d.h = make_float2(0.f, 0.f);
    } else {
      d.m = make_float4(0.f, 0.f, 0.f, 0.f);
      d.h = make_float2(0.f, 0.f);
    }
    return d;
  };

  auto stage = [&](int b, const RowData& d) {
    // interleaved (x,y) so taps read as aligned float4
    rowb[b][5 + 2*l] = make_float2(d.m.x, d.m.z);
    rowb[b][6 + 2*l] = make_float2(d.m.y, d.m.w);
    if (hval) rowb[b][hs] = d.h;
  };

  // fp16 ring of horizontal sums — 11 NAMED register structs (no array, no
  // union; compile-time slot dispatch only)
  RingR s0{}, s1{}, s2{}, s3{}, s4{}, s5{}, s6{}, s7{}, s8{}, s9{}, s10{};
  auto ringRef = [&](auto uc) -> RingR& {
    constexpr int u = decltype(uc)::value;
    if constexpr (u == 0) return s0;  else if constexpr (u == 1) return s1;
    else if constexpr (u == 2) return s2;  else if constexpr (u == 3) return s3;
    else if constexpr (u == 4) return s4;  else if constexpr (u == 5) return s5;
    else if constexpr (u == 6) return s6;  else if constexpr (u == 7) return s7;
    else if constexpr (u == 8) return s8;  else if constexpr (u == 9) return s9;
    else return s10;
  };

  // vertical running sums: (x, y, xy, ss=xx+yy) per col — registers
  float2 vx = make_float2(0.f,0.f), vy = vx, vxy = vx, vss = vx;
  float acc = 0.f;

  // prologue: stage row 0 into buf 0, then 3-deep global prefetch (rows 1..3)
  {
    RowData row0d = loadrow(0);
    stage(0, row0d);
  }
  RowData cur = loadrow(1);
  RowData nxt = loadrow(2);
  RowData nx2 = loadrow(3);

  constexpr float c1 = 0.0001f, c2 = 0.0009f, inv121 = 1.0f/121.0f;

  auto ssim1 = [&](float Sx, float Sy, float Sxy, float Sss) -> float {
    const float mux = Sx*inv121, muy = Sy*inv121;
    const float muxy = mux*muy;
    const float m2   = fmaf(mux, mux, muy*muy);
    const float sgxy = fmaf(Sxy, inv121, -muxy);
    const float sgss = fmaf(Sss, inv121, -m2);
    const float num = fmaf(2.f, muxy, c1) * fmaf(2.f, sgxy, c2);
    const float den = (m2 + c1) * (sgss + c2);
    const float s = num * __builtin_amdgcn_rcpf(den);
    return fminf(fmaxf(s, 0.f), 1.f);
  };

  auto body = [&](auto uc, int it, bool dosub, bool doemit) {
    const int b = it & 1;

    // tap reads FIRST, from the buffer staged LAST iteration
    // taps p=0..11 <-> local cols 2l-5 .. 2l+6 <-> slots 2l .. 2l+11
    const float4* tb = (const float4*)(rowb[b] + 2*l);
    float4 tv[6];
    #pragma unroll
    for (int j = 0; j < 6; ++j) tv[j] = tb[j];

    // stage NEXT row into the other buffer
    stage(b ^ 1, cur);
    cur = nxt; nxt = nx2;
    nx2 = loadrow(it + 4);               // global prefetch 3 rows ahead

    RingR& rr = ringRef(uc);
    const RingR ou = rr;                 // register copy (used only if dosub)

    float sx=0.f, sy=0.f, sxy=0.f, sss=0.f;
    float x0=0.f, y0=0.f, x11=0.f, y11=0.f;
    #pragma unroll
    for (int j = 0; j < 6; ++j) {
      const float4 v = tv[j];            // (x[p], y[p], x[p+1], y[p+1]), p=2j
      if (j == 0) { x0 = v.x; y0 = v.y; }
      sx += v.x; sy += v.y;
      sxy = fmaf(v.x, v.y, sxy);
      sss = fmaf(v.x, v.x, sss);
      sss = fmaf(v.y, v.y, sss);
      if (j < 5) {
        sx += v.z; sy += v.w;
        sxy = fmaf(v.z, v.w, sxy);
        sss = fmaf(v.z, v.z, sss);
        sss = fmaf(v.w, v.w, sss);
      } else { x11 = v.z; y11 = v.w; }
    }

    // col0 window = p0..p10 ; col1 = col0 - p0 + p11
    const float2 hx  = make_float2(sx,  sx - x0 + x11);
    const float2 hy  = make_float2(sy,  sy - y0 + y11);
    const float2 hxy = make_float2(sxy, fmaf(x11, y11, fmaf(-x0, y0, sxy)));
    const float2 hss = make_float2(sss,
        fmaf(x11, x11, fmaf(y11, y11, fmaf(-x0, x0, fmaf(-y0, y0, sss)))));

    // round h to fp16 once; add the rounded value and store the identical
    // rounded value -> later subtract cancels exactly (no drift)
    RingR qu;
    qu.a = __floats2half2_rn(hx.x,  hy.x);
    qu.b = __floats2half2_rn(hxy.x, hss.x);
    qu.c = __floats2half2_rn(hx.y,  hy.y);
    qu.d = __floats2half2_rn(hxy.y, hss.y);
    rr = qu;

    const float2 a0 = __half22float2(qu.a), a1 = __half22float2(qu.b);
    const float2 a2 = __half22float2(qu.c), a3 = __half22float2(qu.d);

    if (dosub) {
      const float2 o0 = __half22float2(ou.a), o1 = __half22float2(ou.b);
      const float2 o2 = __half22float2(ou.c), o3 = __half22float2(ou.d);
      vx.x  -= o0.x; vy.x  -= o0.y; vxy.x -= o1.x; vss.x -= o1.y;
      vx.y  -= o2.x; vy.y  -= o2.y; vxy.y -= o3.x; vss.y -= o3.y;
    }
    vx.x += a0.x; vy.x += a0.y; vxy.x += a1.x; vss.x += a1.y;
    vx.y += a2.x; vy.y += a2.y; vxy.y += a3.x; vss.y += a3.y;

    if (doemit) {
      acc += ssim1(vx.x, vy.x, vxy.x, vss.x);
      acc += ssim1(vx.y, vy.y, vxy.y, vss.y);
    }
  };

  // warmup: rows 0..10 (first emit at it=10) — straight-line, as in R10
  sfor<0, 11>([&](auto uc) { body(uc, decltype(uc)::value, false,
                                  decltype(uc)::value == 10); });

  // steady: rows 11..32 — REAL loop back-edge (do not let the compiler
  // flatten this; R11 showed straight-line 42-body code spills everything)
  #pragma clang loop unroll(disable)
  for (int g = 0; g < 2; ++g) {
    const int base = 11 + 11*g;
    sfor<0, 11>([&](auto uc) { body(uc, base + decltype(uc)::value, true, true); });
  }

  // tail: rows 33..41 — straight-line
  sfor<0, 9>([&](auto uc) { body(uc, 33 + decltype(uc)::value, true, true); });

  // wave reduction -> per-block partial slot (written unconditionally: no
  // memset of d_ws needed, no atomics)
  #pragma unroll
  for (int off = 32; off > 0; off >>= 1) acc += __shfl_down(acc, off, 64);
  if (l == 0) ws[blk] = acc;
}

__global__ void ssim_final(const float* __restrict__ ws, float* __restrict__ out) {
  const int b = blockIdx.x;              // batch element
  const int t = threadIdx.x;             // 64 threads
  const float* p = ws + b * BLKS_PER_B;
  float s = p[t] + p[t + 64] + p[t + 128];
  #pragma unroll
  for (int off = 32; off > 0; off >>= 1) s += __shfl_down(s, off, 64);
  if (t == 0) out[b] = 1.0f - s * (1.0f / (float)(NCH*HH*WW));
}

extern "C" void kernel_launch(void* const* d_in, const int* in_sizes, int n_in,
                              void* d_out, int out_size, void* d_ws, size_t ws_size,
                              hipStream_t stream) {
  const float* pred = (const float*)d_in[0];
  const float* targ = (const float*)d_in[1];
  float* out = (float*)d_out;
  float* ws  = (float*)d_ws;
  ssim_main<<<dim3(NIMG*NCHUNK*NSTRIP), dim3(NT), 0, stream>>>(pred, targ, ws);
  ssim_final<<<dim3(NBATCH), dim3(64), 0, stream>>>(ws, out);
}

// Round 6
// 146.213 us; speedup vs baseline: 2.7496x; 2.7496x over previous
//
#include <hip/hip_runtime.h>
#include <hip/hip_fp16.h>

#define HH 512
#define WW 512
#define NCH 3
#define NBATCH 16
#define NIMG (NBATCH*NCH)     // 48
#define CHUNK 32              // output rows per wave
#define NCHUNK (HH/CHUNK)     // 16
#define NSTRIP 4              // 128-col strips
#define SW 128
#define SLOTS 140             // cols c0-5 .. c0+132 at slot = col-c0+5
#define NT 64                 // one wave per block -> no barriers anywhere
#define NROWS (CHUNK+10)      // 42 input rows per wave
#define BLKS_PER_B (NCH*NCHUNK*NSTRIP)   // 192 partial slots per batch elem

struct RowData { float4 m; float2 h; };
union RingQ { float4 f; __half2 h[4]; };

// R13 = R10 (59us, proven non-spilling) + cross-iteration REGISTER PIPELINING
// of all LDS reads. Theory: at 5 waves/CU the body's 6 tap b128 reads are
// issued ~10 instrs before use -> ~130cyc exposed lgkmcnt wait vs ~140cyc
// VALU = the measured 51% VALUBusy. Fix: during body it (after staging row
// it+1) issue next body's 6 tap reads + ring-old read into NAMED pipeline
// registers; latency hides under this body's compute. Ring write (slot u) vs
// ring prefetch (slot u+1) are different slots - no hazard. Ring STAYS in LDS
// (R9/R11/R12: three register-ring attempts all went to scratch). Math and
// order identical to R7/R10 -> absmax 0.0.
__global__ __launch_bounds__(NT) void ssim_main(
    const float* __restrict__ pred, const float* __restrict__ targ,
    float* __restrict__ ws)
{
  // row staging, 2 buffers: slot s holds (x,y) of col c0+s-5 (same-wave LDS
  // is in-order; no barriers needed — validated R2-R12, absmax 0.0)
  __shared__ __align__(16) float2 rowb[2][SLOTS];
  // fp16 ring of horizontal sums: one 16B word per (slot,lane):
  // {c0:(hx,hy),(hxy,hss), c1:(hx,hy),(hxy,hss)} — read/write as b128
  __shared__ __align__(16) float4 ring[11][NT];

  const int l = threadIdx.x;
  const int blk = blockIdx.x;
  const int img = blk >> 6;              // / (NCHUNK*NSTRIP)
  const int rem = blk & 63;
  const int chunk = rem >> 2;
  const int strip = rem & 3;

  const int r0 = chunk*CHUNK - 5;        // first input row
  const int c0 = strip*SW;

  // zero the pad slots once in BOTH buffers (image-edge strips keep them zero)
  if (l < 10) {
    const int s = (l < 5) ? l : (128 + l);
    rowb[0][s] = make_float2(0.f, 0.f);
    rowb[1][s] = make_float2(0.f, 0.f);
  }

  const size_t ib = (size_t)img * (size_t)(HH*WW);
  const float* pp = pred + ib;
  const float* tp = targ + ib;

  const int cm = c0 + 2*l;               // this lane's 2 main cols
  const int h  = l - 54;                 // halo id 0..9 on lanes 54..63
  const int ch = (h < 5) ? (c0 - 5 + h) : (c0 + 123 + h);   // halo col
  const bool hval = (l >= 54) && ((unsigned)ch < (unsigned)WW);
  const int hs = (h < 5) ? h : (128 + h);                    // halo slot

  auto loadrow = [&](int it) -> RowData {
    RowData d;
    const int r = r0 + it;
    if ((unsigned)r < (unsigned)HH) {    // wave-uniform branch
      const size_t ro = (size_t)r * WW;
      const float2 x = *(const float2*)(pp + ro + cm);
      const float2 y = *(const float2*)(tp + ro + cm);
      d.m = make_float4(x.x, x.y, y.x, y.y);
      if (hval) d.h = make_float2(pp[ro + ch], tp[ro + ch]);
      else      d.h = make_float2(0.f, 0.f);
    } else {
      d.m = make_float4(0.f, 0.f, 0.f, 0.f);
      d.h = make_float2(0.f, 0.f);
    }
    return d;
  };

  auto stage = [&](int b, const RowData& d) {
    // interleaved (x,y) so taps read as aligned float4
    rowb[b][5 + 2*l] = make_float2(d.m.x, d.m.z);
    rowb[b][6 + 2*l] = make_float2(d.m.y, d.m.w);
    if (hval) rowb[b][hs] = d.h;
  };

  // vertical running sums: (x, y, xy, ss=xx+yy) per col — registers
  float2 vx = make_float2(0.f,0.f), vy = vx, vxy = vx, vss = vx;
  float acc = 0.f;

  // LDS->register pipeline: taps + ring-old for the NEXT body (named scalars)
  float4 t0, t1, t2, t3, t4, t5;
  float4 oup = make_float4(0.f, 0.f, 0.f, 0.f);

  // prologue: stage row 0 into buf 0, 3-deep global prefetch (rows 1..3),
  // then prefetch body-0's taps from buf 0 (reads after same-wave writes)
  {
    RowData row0d = loadrow(0);
    stage(0, row0d);
  }
  RowData cur = loadrow(1);
  RowData nxt = loadrow(2);
  RowData nx2 = loadrow(3);
  {
    const float4* tb = (const float4*)(rowb[0] + 2*l);
    t0 = tb[0]; t1 = tb[1]; t2 = tb[2]; t3 = tb[3]; t4 = tb[4]; t5 = tb[5];
  }

  constexpr float c1 = 0.0001f, c2 = 0.0009f, inv121 = 1.0f/121.0f;

  auto ssim1 = [&](float Sx, float Sy, float Sxy, float Sss) -> float {
    const float mux = Sx*inv121, muy = Sy*inv121;
    const float muxy = mux*muy;
    const float m2   = fmaf(mux, mux, muy*muy);
    const float sgxy = fmaf(Sxy, inv121, -muxy);
    const float sgss = fmaf(Sss, inv121, -m2);
    const float num = fmaf(2.f, muxy, c1) * fmaf(2.f, sgxy, c2);
    const float den = (m2 + c1) * (sgss + c2);
    const float s = num * __builtin_amdgcn_rcpf(den);
    return fminf(fmaxf(s, 0.f), 1.f);
  };

  auto body = [&](int it, int slot, bool dosub, bool doemit) {
    const int b = it & 1;
    const int nslot = (slot == 10) ? 0 : (slot + 1);   // next body's ring slot

    // consume the pipeline registers filled during the PREVIOUS body
    const float4 v0 = t0, v1 = t1, v2 = t2, v3 = t3, v4 = t4, v5 = t5;
    RingQ ou; ou.f = oup;

    // stage NEXT row into the other buffer
    stage(b ^ 1, cur);
    cur = nxt; nxt = nx2;
    nx2 = loadrow(it + 4);               // global prefetch 3 rows ahead

    // prefetch for the NEXT body: 6 tap b128 reads from the buffer just
    // staged (in-order LDS -> sees this body's writes) + ring-old of nslot
    // (slot nslot was last written 11 bodies ago; this body writes slot!=nslot)
    {
      const float4* tb = (const float4*)(rowb[b ^ 1] + 2*l);
      t0 = tb[0]; t1 = tb[1]; t2 = tb[2]; t3 = tb[3]; t4 = tb[4]; t5 = tb[5];
      oup = ring[nslot][l];
    }

    float sx=0.f, sy=0.f, sxy=0.f, sss=0.f;
    float x0=0.f, y0=0.f, x11=0.f, y11=0.f;
    #pragma unroll
    for (int j = 0; j < 6; ++j) {
      const float4 v = (j==0)?v0:(j==1)?v1:(j==2)?v2:(j==3)?v3:(j==4)?v4:v5;
      if (j == 0) { x0 = v.x; y0 = v.y; }
      sx += v.x; sy += v.y;
      sxy = fmaf(v.x, v.y, sxy);
      sss = fmaf(v.x, v.x, sss);
      sss = fmaf(v.y, v.y, sss);
      if (j < 5) {
        sx += v.z; sy += v.w;
        sxy = fmaf(v.z, v.w, sxy);
        sss = fmaf(v.z, v.z, sss);
        sss = fmaf(v.w, v.w, sss);
      } else { x11 = v.z; y11 = v.w; }
    }

    // col0 window = p0..p10 ; col1 = col0 - p0 + p11
    const float2 hx  = make_float2(sx,  sx - x0 + x11);
    const float2 hy  = make_float2(sy,  sy - y0 + y11);
    const float2 hxy = make_float2(sxy, fmaf(x11, y11, fmaf(-x0, y0, sxy)));
    const float2 hss = make_float2(sss,
        fmaf(x11, x11, fmaf(y11, y11, fmaf(-x0, x0, fmaf(-y0, y0, sss)))));

    // round h to fp16 once; add the rounded value and store the identical
    // rounded value -> later subtract cancels exactly (no drift)
    RingQ qu;
    qu.h[0] = __floats2half2_rn(hx.x,  hy.x);
    qu.h[1] = __floats2half2_rn(hxy.x, hss.x);
    qu.h[2] = __floats2half2_rn(hx.y,  hy.y);
    qu.h[3] = __floats2half2_rn(hxy.y, hss.y);
    ring[slot][l] = qu.f;                // ONE b128 write
    const float2 a0 = __half22float2(qu.h[0]), a1 = __half22float2(qu.h[1]);
    const float2 a2 = __half22float2(qu.h[2]), a3 = __half22float2(qu.h[3]);

    if (dosub) {
      const float2 oxy0 = __half22float2(ou.h[0]), ops0 = __half22float2(ou.h[1]);
      const float2 oxy1 = __half22float2(ou.h[2]), ops1 = __half22float2(ou.h[3]);
      vx.x  -= oxy0.x; vy.x  -= oxy0.y; vxy.x -= ops0.x; vss.x -= ops0.y;
      vx.y  -= oxy1.x; vy.y  -= oxy1.y; vxy.y -= ops1.x; vss.y -= ops1.y;
    }
    vx.x += a0.x; vy.x += a0.y; vxy.x += a1.x; vss.x += a1.y;
    vx.y += a2.x; vy.y += a2.y; vxy.y += a3.x; vss.y += a3.y;

    if (doemit) {
      acc += ssim1(vx.x, vy.x, vxy.x, vss.x);
      acc += ssim1(vx.y, vy.y, vxy.y, vss.y);
    }
  };

  // 42 input rows: warmup 11 (first emit at it=10), steady 2x11, tail 9
  #pragma unroll
  for (int u = 0; u < 11; ++u) body(u, u, false, u == 10);
  for (int g = 0; g < 2; ++g) {
    #pragma unroll
    for (int u = 0; u < 11; ++u) body(11 + 11*g + u, u, true, true);
  }
  #pragma unroll
  for (int u = 0; u < 9; ++u) body(33 + u, u, true, true);

  // wave reduction -> per-block partial slot (written unconditionally: no
  // memset of d_ws needed, no atomics)
  #pragma unroll
  for (int off = 32; off > 0; off >>= 1) acc += __shfl_down(acc, off, 64);
  if (l == 0) ws[blk] = acc;
}

__global__ void ssim_final(const float* __restrict__ ws, float* __restrict__ out) {
  const int b = blockIdx.x;              // batch element
  const int t = threadIdx.x;             // 64 threads
  const float* p = ws + b * BLKS_PER_B;
  float s = p[t] + p[t + 64] + p[t + 128];
  #pragma unroll
  for (int off = 32; off > 0; off >>= 1) s += __shfl_down(s, off, 64);
  if (t == 0) out[b] = 1.0f - s * (1.0f / (float)(NCH*HH*WW));
}

extern "C" void kernel_launch(void* const* d_in, const int* in_sizes, int n_in,
                              void* d_out, int out_size, void* d_ws, size_t ws_size,
                              hipStream_t stream) {
  const float* pred = (const float*)d_in[0];
  const float* targ = (const float*)d_in[1];
  float* out = (float*)d_out;
  float* ws  = (float*)d_ws;
  ssim_main<<<dim3(NIMG*NCHUNK*NSTRIP), dim3(NT), 0, stream>>>(pred, targ, ws);
  ssim_final<<<dim3(NBATCH), dim3(64), 0, stream>>>(ws, out);
}

// Round 8
// 145.359 us; speedup vs baseline: 2.7657x; 1.0059x over previous
//
#include <hip/hip_runtime.h>

#define HH 512
#define WW 512
#define NCH 3
#define NBATCH 16
#define NIMG (NBATCH*NCH)     // 48
#define CHUNK 32              // output rows per wave
#define NCHUNK (HH/CHUNK)     // 16
#define NSTRIP 4              // 128-col strips
#define SW 128
#define SLOTS 142             // pad=6: col c <-> slot c-c0+6, slots 0..141
#define NT 64                 // one wave per block -> no barriers anywhere
#define BLKS_PER_B (NCH*NCHUNK*NSTRIP)   // 192 partial slots per batch elem

struct RowData { float4 m; float2 h; };

// R15 = R14 (ring eliminated: vertical slide over raw sums) + warmup-subtract
// FIX. R14 bug: it subtracted row it-11 unconditionally; for chunk>=1 that is
// a VALID image row during warmup (r0+it-11 = 32*chunk-16 >= 0) -> real data
// subtracted from empty accumulators -> absmax 0.31 on 15/16 chunks. Correct
// semantics: the pre-window is EMPTY — old row must be zero when the
// iteration index it-11 < 0, regardless of image bounds. loadold() adds that
// (wave-uniform) check; steady-loop codegen unchanged.
//  Structure rationale (R7-R13): at 5 waves/CU (LDS-capped by the 11.3KB
//  fp16 ring) each wave's ~30us VALU and ~30us LDS serialize in antiphase;
//  register-ring died 3x to scratch (R9/R11/R12). So the ring is gone:
//  per-column vertical running sums (Sx,Sy,Sxy,Sss) live in registers; the
//  row leaving the window is RE-LOADED from global (11-row reuse -> L2 hit)
//  and its products recomputed. Per body: stage 4 sums/col into two float2
//  LDS arrays (pad=6 -> ONE conflict-free b128 write each) and do the
//  horizontal 11-tap window as pure adds (7 conflict-free b128 reads each).
//  LDS 13824 -> 2304B: occupancy 5 -> 12 blocks/CU (grid cap); VALU and LDS
//  pipes overlap across 3 waves/SIMD. Full f32 (absmax ~1e-5, not bit-zero).
__global__ __launch_bounds__(NT) void ssim_main(
    const float* __restrict__ pred, const float* __restrict__ targ,
    float* __restrict__ ws)
{
  // vertical-sum staging: slot s holds col c0+s-6 (same-wave in-order LDS;
  // no barriers — validated R2-R13)
  __shared__ __align__(16) float2 arrA[SLOTS];   // (Sx, Sy) per col
  __shared__ __align__(16) float2 arrB[SLOTS];   // (Sxy, Sss) per col

  const int l = threadIdx.x;
  const int blk = blockIdx.x;
  const int img = blk >> 6;              // / (NCHUNK*NSTRIP)
  const int rem = blk & 63;
  const int chunk = rem >> 2;
  const int strip = rem & 3;

  const int r0 = chunk*CHUNK - 5;        // first input row
  const int c0 = strip*SW;

  const size_t ib = (size_t)img * (size_t)(HH*WW);
  const float* pp = pred + ib;
  const float* tp = targ + ib;

  const int cm = c0 + 2*l;               // this lane's 2 main cols
  const int h  = l - 54;                 // halo id 0..9 on lanes 54..63
  const int ch = (h < 5) ? (c0 - 5 + h) : (c0 + 123 + h);   // halo col
  const bool hval = (l >= 54) && ((unsigned)ch < (unsigned)WW);
  const int hs = (h < 5) ? (1 + h) : (129 + h);  // halo slot (pad=6)

  auto loadrow = [&](int it) -> RowData {
    RowData d;
    const int r = r0 + it;
    if ((unsigned)r < (unsigned)HH) {    // wave-uniform branch
      const size_t ro = (size_t)r * WW;
      const float2 x = *(const float2*)(pp + ro + cm);
      const float2 y = *(const float2*)(tp + ro + cm);
      d.m = make_float4(x.x, x.y, y.x, y.y);
      if (hval) d.h = make_float2(pp[ro + ch], tp[ro + ch]);
      else      d.h = make_float2(0.f, 0.f);
    } else {
      d.m = make_float4(0.f, 0.f, 0.f, 0.f);
      d.h = make_float2(0.f, 0.f);
    }
    return d;
  };

  // old-row stream: zero when the ITERATION index is pre-window (it<0),
  // independent of image bounds (which loadrow already zero-pads).
  auto loadold = [&](int it) -> RowData {
    if (it >= 0) return loadrow(it);     // wave-uniform branch
    RowData d;
    d.m = make_float4(0.f, 0.f, 0.f, 0.f);
    d.h = make_float2(0.f, 0.f);
    return d;
  };

  // vertical running sums over the 11-row window — all registers, no history
  float vx0=0.f, vy0=0.f, vxy0=0.f, vss0=0.f;    // main col 0 (cm)
  float vx1=0.f, vy1=0.f, vxy1=0.f, vss1=0.f;    // main col 1 (cm+1)
  float vxh=0.f, vyh=0.f, vxyh=0.f, vssh=0.f;    // halo col (lanes 54..63)
  float acc = 0.f;

  // prefetch: new-row stream 3-deep (HBM), old-row stream 1-deep (L2 hit)
  RowData curN = loadrow(0);
  RowData nxtN = loadrow(1);
  RowData nx2N = loadrow(2);
  RowData curO = loadold(-11);           // pre-window -> zeros

  constexpr float c1 = 0.0001f, c2 = 0.0009f, inv121 = 1.0f/121.0f;

  auto ssim1 = [&](float Sx, float Sy, float Sxy, float Sss) -> float {
    const float mux = Sx*inv121, muy = Sy*inv121;
    const float muxy = mux*muy;
    const float m2   = fmaf(mux, mux, muy*muy);
    const float sgxy = fmaf(Sxy, inv121, -muxy);
    const float sgss = fmaf(Sss, inv121, -m2);
    const float num = fmaf(2.f, muxy, c1) * fmaf(2.f, sgxy, c2);
    const float den = (m2 + c1) * (sgss + c2);
    const float s = num * __builtin_amdgcn_rcpf(den);
    return fminf(fmaxf(s, 0.f), 1.f);
  };

  auto body = [&](int it, bool doemit) {
    // 1) vertical window slide: add new row, subtract old row (zero if
    //    pre-window or out of image). Products recomputed identically on add
    //    and subtract -> drift is ~ulp-level only.
    {
      const float xn0 = curN.m.x, xn1 = curN.m.y;
      const float yn0 = curN.m.z, yn1 = curN.m.w;
      const float xo0 = curO.m.x, xo1 = curO.m.y;
      const float yo0 = curO.m.z, yo1 = curO.m.w;
      vx0  += xn0 - xo0;  vy0  += yn0 - yo0;
      vx1  += xn1 - xo1;  vy1  += yn1 - yo1;
      vxy0 += xn0*yn0 - xo0*yo0;
      vxy1 += xn1*yn1 - xo1*yo1;
      vss0 += fmaf(xn0, xn0, yn0*yn0) - fmaf(xo0, xo0, yo0*yo0);
      vss1 += fmaf(xn1, xn1, yn1*yn1) - fmaf(xo1, xo1, yo1*yo1);
      const float xnh = curN.h.x, ynh = curN.h.y;
      const float xoh = curO.h.x, yoh = curO.h.y;
      vxh  += xnh - xoh;  vyh  += ynh - yoh;
      vxyh += xnh*ynh - xoh*yoh;
      vssh += fmaf(xnh, xnh, ynh*ynh) - fmaf(xoh, xoh, yoh*yoh);
    }

    // 2) advance prefetch streams (old row issued a full body before use)
    curN = nxtN; nxtN = nx2N;
    nx2N = loadrow(it + 3);
    RowData oN = loadold(it - 10);       // old row for body it+1

    // 3) stage vertical sums: ONE aligned conflict-free b128 per array
    //    (byte 48+16l, 16B/lane stride) + halo b64 on 10 lanes
    *(float4*)(arrA + 6 + 2*l) = make_float4(vx0, vy0, vx1, vy1);
    *(float4*)(arrB + 6 + 2*l) = make_float4(vxy0, vss0, vxy1, vss1);
    if (l >= 54) {
      arrA[hs] = make_float2(vxh, vyh);
      arrB[hs] = make_float2(vxyh, vssh);
    }

    // 4) horizontal 11-tap window, pure adds. Element j of the b128 read at
    //    (float4*)arrA + l + j covers slots {2l+2j, 2l+2j+1}; col0 window =
    //    slots 2l+1..2l+11, col1 = col0 - slot(2l+1) + slot(2l+12).
    const float4* ta = (const float4*)(arrA) + l;
    const float4 a0v = ta[0], a1v = ta[1], a2v = ta[2], a3v = ta[3],
                 a4v = ta[4], a5v = ta[5], a6v = ta[6];
    const float4* tb = (const float4*)(arrB) + l;
    const float4 b0v = tb[0], b1v = tb[1], b2v = tb[2], b3v = tb[3],
                 b4v = tb[4], b5v = tb[5], b6v = tb[6];

    float Sx = a0v.z, Sy = a0v.w;
    Sx += a1v.x; Sy += a1v.y;  Sx += a1v.z; Sy += a1v.w;
    Sx += a2v.x; Sy += a2v.y;  Sx += a2v.z; Sy += a2v.w;
    Sx += a3v.x; Sy += a3v.y;  Sx += a3v.z; Sy += a3v.w;
    Sx += a4v.x; Sy += a4v.y;  Sx += a4v.z; Sy += a4v.w;
    Sx += a5v.x; Sy += a5v.y;  Sx += a5v.z; Sy += a5v.w;
    const float Sx1 = Sx - a0v.z + a6v.x;
    const float Sy1 = Sy - a0v.w + a6v.y;

    float Sxy = b0v.z, Sss = b0v.w;
    Sxy += b1v.x; Sss += b1v.y;  Sxy += b1v.z; Sss += b1v.w;
    Sxy += b2v.x; Sss += b2v.y;  Sxy += b2v.z; Sss += b2v.w;
    Sxy += b3v.x; Sss += b3v.y;  Sxy += b3v.z; Sss += b3v.w;
    Sxy += b4v.x; Sss += b4v.y;  Sxy += b4v.z; Sss += b4v.w;
    Sxy += b5v.x; Sss += b5v.y;  Sxy += b5v.z; Sss += b5v.w;
    const float Sxy1 = Sxy - b0v.z + b6v.x;
    const float Sss1 = Sss - b0v.w + b6v.y;

    if (doemit) {
      acc += ssim1(Sx,  Sy,  Sxy,  Sss);
      acc += ssim1(Sx1, Sy1, Sxy1, Sss1);
    }
    curO = oN;
  };

  // 42 input rows: warmup 10 (no emit), then 32 emitting bodies.
  // Moderate unroll with REAL back-edges (R11: 42 straight-line bodies ->
  // giant live ranges -> 256 VGPR + 300MB scratch; never again).
  #pragma clang loop unroll_count(2)
  for (int it = 0; it < 10; ++it) body(it, false);
  #pragma clang loop unroll_count(2)
  for (int it = 10; it < 42; ++it) body(it, true);

  // wave reduction -> per-block partial slot (written unconditionally: no
  // memset of d_ws needed, no atomics)
  #pragma unroll
  for (int off = 32; off > 0; off >>= 1) acc += __shfl_down(acc, off, 64);
  if (l == 0) ws[blk] = acc;
}

__global__ void ssim_final(const float* __restrict__ ws, float* __restrict__ out) {
  const int b = blockIdx.x;              // batch element
  const int t = threadIdx.x;             // 64 threads
  const float* p = ws + b * BLKS_PER_B;
  float s = p[t] + p[t + 64] + p[t + 128];
  #pragma unroll
  for (int off = 32; off > 0; off >>= 1) s += __shfl_down(s, off, 64);
  if (t == 0) out[b] = 1.0f - s * (1.0f / (float)(NCH*HH*WW));
}

extern "C" void kernel_launch(void* const* d_in, const int* in_sizes, int n_in,
                              void* d_out, int out_size, void* d_ws, size_t ws_size,
                              hipStream_t stream) {
  const float* pred = (const float*)d_in[0];
  const float* targ = (const float*)d_in[1];
  float* out = (float*)d_out;
  float* ws  = (float*)d_ws;
  ssim_main<<<dim3(NIMG*NCHUNK*NSTRIP), dim3(NT), 0, stream>>>(pred, targ, ws);
  ssim_final<<<dim3(NBATCH), dim3(64), 0, stream>>>(ws, out);
}